// Round 14
// baseline (126.623 us; speedup 1.0000x reference)
//
#include <hip/hip_runtime.h>
#include <hip/hip_bf16.h>

// Problem constants
#define BB 4
#define SS 2048
#define EE 512
#define HH 8
#define DKK 64
#define NQQ 8
#define BS (BB * SS)   // 8192 rows

typedef __attribute__((ext_vector_type(4))) float f32x4;
typedef __attribute__((ext_vector_type(16))) float f32x16;
typedef __fp16 fp16x2 __attribute__((ext_vector_type(2)));   // cvt_pkrtz return type
typedef _Float16 f16x8 __attribute__((ext_vector_type(8)));
typedef unsigned short u16;
typedef unsigned int u32;

union U4H8 { uint4 u; f16x8 h; };
union PK8 { fp16x2 p[4]; f16x8 h; };

__device__ __forceinline__ u16 f2h(float f) {
    _Float16 hv = (_Float16)f;
    return *reinterpret_cast<u16*>(&hv);
}
__device__ __forceinline__ float h2f(u16 u) {
    _Float16 h = *reinterpret_cast<_Float16*>(&u);
    return (float)h;
}

// ---------------------------------------------------------------------------
// P1: x fp32 -> xh (f16) + xl (f16 residual).
// ---------------------------------------------------------------------------
__global__ __launch_bounds__(256) void cvt2_kernel(
    const float4* __restrict__ in, uint2* __restrict__ xh, uint2* __restrict__ xl, int n4)
{
    int i = blockIdx.x * 256 + threadIdx.x;
    if (i >= n4) return;
    float4 a = in[i];
    u16 h0 = f2h(a.x), h1 = f2h(a.y), h2 = f2h(a.z), h3 = f2h(a.w);
    u16 l0 = f2h(a.x - h2f(h0)), l1 = f2h(a.y - h2f(h1));
    u16 l2 = f2h(a.z - h2f(h2)), l3 = f2h(a.w - h2f(h3));
    xh[i] = make_uint2((u32)h0 | ((u32)h1 << 16), (u32)h2 | ((u32)h3 << 16));
    xl[i] = make_uint2((u32)l0 | ((u32)l1 << 16), (u32)l2 | ((u32)l3 << 16));
}

// ---------------------------------------------------------------------------
// P2: pack+transpose the 64 live Q/K weight cols each into Wqk[128][512] f16.
// ---------------------------------------------------------------------------
__global__ __launch_bounds__(256) void wqk_pack_kernel(
    const float* __restrict__ Wq, const float* __restrict__ Wk,
    u16* __restrict__ Wh)
{
    const int n = blockIdx.x;                  // 0..127
    const int col = (((n & 63) >> 3) << 6) | (n & 7);
    const float* src = (n < 64) ? Wq : Wk;
    for (int k = threadIdx.x; k < EE; k += 256) {
        Wh[(size_t)n * EE + k] = f2h(src[(size_t)k * EE + col]);
    }
}

// ---------------------------------------------------------------------------
// P3: W [512][512] f32 -> WT [512][512] f16 transposed (for Wv, Wo).
// ---------------------------------------------------------------------------
__global__ __launch_bounds__(256) void wtrans_kernel(
    const float* __restrict__ W, u16* __restrict__ WT)
{
    __shared__ float ts[64][65];
    const int kt0 = blockIdx.x * 64, nt0 = blockIdx.y * 64;
    const int tid = threadIdx.x;
    #pragma unroll
    for (int i = 0; i < 4; ++i) {
        int c = tid + i * 256;
        int kr = c >> 4, nc = (c & 15) * 4;
        float4 t = *reinterpret_cast<const float4*>(&W[(size_t)(kt0 + kr) * EE + nt0 + nc]);
        ts[kr][nc] = t.x; ts[kr][nc + 1] = t.y; ts[kr][nc + 2] = t.z; ts[kr][nc + 3] = t.w;
    }
    __syncthreads();
    const int n = tid >> 2, k0 = (tid & 3) * 16;
    u32 o[8];
    #pragma unroll
    for (int j = 0; j < 8; ++j) {
        o[j] = (u32)f2h(ts[k0 + 2 * j][n]) | ((u32)f2h(ts[k0 + 2 * j + 1][n]) << 16);
    }
    uint4* dst = reinterpret_cast<uint4*>(&WT[(size_t)(nt0 + n) * EE + kt0 + k0]);
    dst[0] = make_uint4(o[0], o[1], o[2], o[3]);
    dst[1] = make_uint4(o[4], o[5], o[6], o[7]);
}

// ---------------------------------------------------------------------------
// QK projection via MFMA, double-f16 (2 passes: xh*W + xl*W). Round-12 form
// (reg-staged prefetch). Epilogue: cos(proj + bias); K pre-scaled by log2(e).
// ---------------------------------------------------------------------------
__global__ __launch_bounds__(256) void qk_mfma_kernel(
    const u16* __restrict__ xh, const u16* __restrict__ xl,
    const u16* __restrict__ Wh,
    const float* __restrict__ bq, const float* __restrict__ bk,
    u16* __restrict__ qf, u16* __restrict__ kf)
{
    __shared__ u16 Asl[64 * 64];
    __shared__ u16 Bsl[64 * 64];

    const int tid = threadIdx.x;
    const int lane = tid & 63;
    const int ww = tid >> 6;
    const int wr = ww >> 1, wc = ww & 1;
    const int tx = lane & 15, tyq = lane >> 4;
    const int m0 = blockIdx.x * 64;
    const int isK = blockIdx.y;
    const int nbase = isK * 64;

    const int c0 = tid, c1 = tid + 256;
    const int r0 = c0 >> 3, o0 = (c0 & 7) * 8, d0 = r0 * 64 + (((c0 & 7) ^ (r0 & 7)) * 8);
    const int r1 = c1 >> 3, o1 = (c1 & 7) * 8, d1 = r1 * 64 + (((c1 & 7) ^ (r1 & 7)) * 8);

    uint4 pa0, pa1, pb0, pb1;
    auto ldi = [&](int it) {
        int pass = it >> 3, k0 = (it & 7) * 64;
        const u16* Ab = pass ? xl : xh;
        pa0 = *reinterpret_cast<const uint4*>(&Ab[(size_t)(m0 + r0) * EE + k0 + o0]);
        pb0 = *reinterpret_cast<const uint4*>(&Wh[(size_t)(nbase + r0) * EE + k0 + o0]);
        pa1 = *reinterpret_cast<const uint4*>(&Ab[(size_t)(m0 + r1) * EE + k0 + o1]);
        pb1 = *reinterpret_cast<const uint4*>(&Wh[(size_t)(nbase + r1) * EE + k0 + o1]);
    };
    auto st = [&]() {
        *reinterpret_cast<uint4*>(&Asl[d0]) = pa0;
        *reinterpret_cast<uint4*>(&Bsl[d0]) = pb0;
        *reinterpret_cast<uint4*>(&Asl[d1]) = pa1;
        *reinterpret_cast<uint4*>(&Bsl[d1]) = pb1;
    };

    f32x4 acc[2][2];
    #pragma unroll
    for (int mt = 0; mt < 2; ++mt)
        #pragma unroll
        for (int nt = 0; nt < 2; ++nt) acc[mt][nt] = (f32x4)(0.f);

    const int bkx = tx & 7;
    ldi(0);
    for (int it = 0; it < 16; ++it) {
        __syncthreads();
        st();
        if (it < 15) ldi(it + 1);
        __syncthreads();
        #pragma unroll
        for (int kb = 0; kb < 2; ++kb) {
            f16x8 af[2], bfg[2];
            const int kblk = ((kb * 4 + tyq) ^ bkx) * 8;
            #pragma unroll
            for (int mt = 0; mt < 2; ++mt)
                af[mt] = *reinterpret_cast<const f16x8*>(&Asl[(wr * 32 + mt * 16 + tx) * 64 + kblk]);
            #pragma unroll
            for (int nt = 0; nt < 2; ++nt)
                bfg[nt] = *reinterpret_cast<const f16x8*>(&Bsl[(wc * 32 + nt * 16 + tx) * 64 + kblk]);
            #pragma unroll
            for (int mt = 0; mt < 2; ++mt)
                #pragma unroll
                for (int nt = 0; nt < 2; ++nt)
                    acc[mt][nt] = __builtin_amdgcn_mfma_f32_16x16x32_f16(
                        af[mt], bfg[nt], acc[mt][nt], 0, 0, 0);
        }
    }

    const float* bias = isK ? bk : bq;
    const float scale = isK ? 1.44269504f : 1.0f;   // log2(e) prescale on K
    u16* dst = isK ? kf : qf;
    #pragma unroll
    for (int mt = 0; mt < 2; ++mt) {
        #pragma unroll
        for (int nt = 0; nt < 2; ++nt) {
            int nl = wc * 32 + nt * 16 + tx;
            int h = nl >> 3, f = nl & 7;
            float bcol = bias[h * 64 + f];
            #pragma unroll
            for (int r = 0; r < 4; ++r) {
                int s = m0 + wr * 32 + mt * 16 + tyq * 4 + r;
                float c = __cosf(acc[mt][nt][r] + bcol) * scale;
                size_t bh = (size_t)((s >> 11) * HH + h);
                dst[(bh * SS + (s & 2047)) * 8 + f] = f2h(c);
            }
        }
    }
}

// ---------------------------------------------------------------------------
// f16 MFMA GEMM, BM=128 x BN=64 x BK=64 (4 waves of 64x32, acc[4][2]):
// 16 MFMA per 12 ds_read_b128 per wave K-step (was 8:8 at 64x64).
// Reg-staged prefetch + XOR-swizzled LDS (round-12 verified pattern).
// MODE 0: out fp32 [8192][512], bias[n] (out-proj); grid (BS/128, EE/64).
// MODE 1: out f16 VT2 cells (tau-baked); A=WvT so 128 m-rows = 2 heads;
//   grid (EE/128, BS/64). addr(u16) = slab + cell*512 + d*8 + slot.
// ---------------------------------------------------------------------------
template<int MODE>
__global__ __launch_bounds__(256) void mfma_gemm_kernel(
    const u16* __restrict__ A, const u16* __restrict__ Bm,
    const float* __restrict__ bias, float* __restrict__ outf, u16* __restrict__ outb)
{
    __shared__ u16 smem[12288];   // Asl 128x64 (8192), Bsl 64x64 (4096); 24 KB
    u16* Asl = smem;
    u16* Bsl = smem + 8192;

    const int tid = threadIdx.x;
    const int lane = tid & 63;
    const int ww = tid >> 6;
    const int wr = ww >> 1, wc = ww & 1;        // wave = 64 rows x 32 cols
    const int tx = lane & 15, tyq = lane >> 4;
    const int m0 = blockIdx.x * 128, n0 = blockIdx.y * 64;

    uint4 pa[4], pb[2];
    auto ld = [&](int ks) {
        int k0 = ks * 64;
        #pragma unroll
        for (int i = 0; i < 4; ++i) {
            int c = tid + i * 256;
            int r = c >> 3, o = (c & 7) * 8;
            pa[i] = *reinterpret_cast<const uint4*>(&A[(size_t)(m0 + r) * EE + k0 + o]);
        }
        #pragma unroll
        for (int i = 0; i < 2; ++i) {
            int c = tid + i * 256;
            int r = c >> 3, o = (c & 7) * 8;
            pb[i] = *reinterpret_cast<const uint4*>(&Bm[(size_t)(n0 + r) * EE + k0 + o]);
        }
    };
    auto st = [&]() {
        #pragma unroll
        for (int i = 0; i < 4; ++i) {
            int c = tid + i * 256;
            int r = c >> 3, e = c & 7;
            *reinterpret_cast<uint4*>(&Asl[r * 64 + ((e ^ (r & 7)) * 8)]) = pa[i];
        }
        #pragma unroll
        for (int i = 0; i < 2; ++i) {
            int c = tid + i * 256;
            int r = c >> 3, e = c & 7;
            *reinterpret_cast<uint4*>(&Bsl[r * 64 + ((e ^ (r & 7)) * 8)]) = pb[i];
        }
    };

    f32x4 acc[4][2];
    #pragma unroll
    for (int mt = 0; mt < 4; ++mt)
        #pragma unroll
        for (int nt = 0; nt < 2; ++nt) acc[mt][nt] = (f32x4)(0.f);

    const int bkx = tx & 7;
    ld(0);
    for (int ks = 0; ks < 8; ++ks) {
        __syncthreads();
        st();
        if (ks < 7) ld(ks + 1);
        __syncthreads();
        #pragma unroll
        for (int kb = 0; kb < 2; ++kb) {
            f16x8 af[4], bfg[2];
            const int kblk = ((kb * 4 + tyq) ^ bkx) * 8;
            #pragma unroll
            for (int mt = 0; mt < 4; ++mt)
                af[mt] = *reinterpret_cast<const f16x8*>(&Asl[(wr * 64 + mt * 16 + tx) * 64 + kblk]);
            #pragma unroll
            for (int nt = 0; nt < 2; ++nt)
                bfg[nt] = *reinterpret_cast<const f16x8*>(&Bsl[(wc * 32 + nt * 16 + tx) * 64 + kblk]);
            #pragma unroll
            for (int mt = 0; mt < 4; ++mt)
                #pragma unroll
                for (int nt = 0; nt < 2; ++nt)
                    acc[mt][nt] = __builtin_amdgcn_mfma_f32_16x16x32_f16(
                        af[mt], bfg[nt], acc[mt][nt], 0, 0, 0);
        }
    }

    if (MODE == 0) {
        #pragma unroll
        for (int mt = 0; mt < 4; ++mt) {
            #pragma unroll
            for (int nt = 0; nt < 2; ++nt) {
                int gcol = n0 + wc * 32 + nt * 16 + tx;
                float bcol = bias[gcol];
                #pragma unroll
                for (int r = 0; r < 4; ++r) {
                    int grow = m0 + wr * 64 + mt * 16 + tyq * 4 + r;
                    outf[(size_t)grow * EE + gcol] = acc[mt][nt][r] + bcol;
                }
            }
        }
    } else {
        // retile: stage C as L[dl][kl] f16 in LDS (128 x 64, stride 66)
        __syncthreads();   // main-loop LDS reads complete before reuse
        #pragma unroll
        for (int mt = 0; mt < 4; ++mt) {
            #pragma unroll
            for (int nt = 0; nt < 2; ++nt) {
                int kl = wc * 32 + nt * 16 + tx;
                #pragma unroll
                for (int r = 0; r < 4; ++r) {
                    int dl = wr * 64 + mt * 16 + tyq * 4 + r;
                    float vb = acc[mt][nt][r] + bias[m0 + dl];
                    smem[dl * 66 + kl] = f2h(vb);
                }
            }
        }
        __syncthreads();
        // writeout: 1024 items = 128 d-rows x 8 cells of 16B
        const int bb = n0 >> 11;
        const int cell0 = (n0 & 2047) >> 3;
        #pragma unroll
        for (int i = 0; i < 4; ++i) {
            int item = tid + i * 256;
            int d128 = item & 127, ci = item >> 7;       // ci 0..7
            int kb2 = 16 * (ci >> 1) + 4 * (ci & 1);
            int hoff = d128 >> 6, d = d128 & 63;
            size_t slab = (size_t)(bb * HH + (m0 >> 6) + hoff) * (SS * DKK);
            u16 g[8];
            #pragma unroll
            for (int j = 0; j < 8; ++j) {
                int klocal = kb2 + (j & 3) + 8 * (j >> 2);
                g[j] = smem[d128 * 66 + klocal];
            }
            uint4 p;
            p.x = (u32)g[0] | ((u32)g[1] << 16);
            p.y = (u32)g[2] | ((u32)g[3] << 16);
            p.z = (u32)g[4] | ((u32)g[5] << 16);
            p.w = (u32)g[6] | ((u32)g[7] << 16);
            *reinterpret_cast<uint4*>(&outb[slab + (size_t)(cell0 + ci) * 512 + d * 8]) = p;
        }
    }
}

// ---------------------------------------------------------------------------
// Attention v10 (round-13, passed): barrier-free LDS-free main loop,
// direct-L2 VT2 cell reads, exp2 on pre-scaled K, setprio around PV,
// pairwise cvt_pkrtz PA packing. 4 waves = 2 q-sub x 2 k-slices. Grid 1024.
// ---------------------------------------------------------------------------
__global__ __launch_bounds__(256, 4) void attn_v10_kernel(
    const u16* __restrict__ qf, const u16* __restrict__ kf,
    const u16* __restrict__ VT2, u16* __restrict__ attb)
{
    __shared__ float fsh[128 * 33];   // 16.9 KB combine scratch

    const int tid = threadIdx.x;
    const int lane = tid & 63;
    const int wv = tid >> 6;
    const int kslice = wv >> 1;
    const int qw = wv & 1;
    const int l31 = lane & 31;
    const int hi = lane >> 5;

    // XCD-aware swizzle: all 32 q-blocks of a (b,h) on one XCD
    const int bid = blockIdx.x;
    const int xcd = bid & 7, sub = bid >> 3;
    const int bh = (xcd << 2) | (sub >> 5);
    const int q0 = (sub & 31) * 64;

    const u16* __restrict__ qfb = qf + (size_t)bh * SS * 8;
    const u16* __restrict__ kfb = kf + (size_t)bh * SS * 8;
    const u16* __restrict__ V2b = VT2 + (size_t)bh * SS * DKK;

    const uint4 z4 = make_uint4(0u, 0u, 0u, 0u);

    // Q B-frag (loop-invariant): B[k=8hi+j][n=q=l31]; feats 8..15 pad=0
    U4H8 qb;
    qb.u = hi ? z4 : *reinterpret_cast<const uint4*>(&qfb[(size_t)(q0 + qw * 32 + l31) * 8]);
    const f16x8 QB = qb.h;

    f32x16 acc0 = (f32x16)(0.f), acc1 = (f32x16)(0.f);
    float z = 0.f;

    const int ks_off = kslice * 1024;

    // V frag loader: (t, s) -> 4 uint4 [c*2 + dblk]
    auto vld = [&](int t, int s, uint4* dst) {
        const int K0 = ks_off + t * 64 + s * 32;
        #pragma unroll
        for (int c = 0; c < 2; ++c) {
            const size_t cb = (size_t)((((K0 >> 4) + c) << 1) + hi) * 512;
            dst[c * 2]     = *reinterpret_cast<const uint4*>(&V2b[cb + l31 * 8]);
            dst[c * 2 + 1] = *reinterpret_cast<const uint4*>(&V2b[cb + (32 + l31) * 8]);
        }
    };

    U4H8 kc0, kc1, kn0, kn1;
    auto ldk = [&](int t, U4H8& a, U4H8& b) {
        int kt = ks_off + t * 64;
        a.u = hi ? z4 : *reinterpret_cast<const uint4*>(&kfb[(size_t)(kt + l31) * 8]);
        b.u = hi ? z4 : *reinterpret_cast<const uint4*>(&kfb[(size_t)(kt + 32 + l31) * 8]);
    };

    uint4 vA[4], vB[4];
    ldk(0, kc0, kc1);
    vld(0, 0, vA);

    for (int t = 0; t < 16; ++t) {
        // ---- s = 0 (uses kc0, vA) ----
        vld(t, 1, vB);
        if (t < 15) ldk(t + 1, kn0, kn1);
        {
            f32x16 sim = (f32x16)(0.f);
            sim = __builtin_amdgcn_mfma_f32_32x32x16_f16(kc0.h, QB, sim, 0, 0, 0);
            float w[16];
            #pragma unroll
            for (int r = 0; r < 16; ++r) w[r] = __builtin_amdgcn_exp2f(sim[r]);  // K pre-scaled
            float zp = 0.f;
            #pragma unroll
            for (int r = 0; r < 8; ++r) zp += (w[2 * r] + w[2 * r + 1]);
            z += zp;
            __builtin_amdgcn_s_setprio(1);
            #pragma unroll
            for (int c = 0; c < 2; ++c) {
                PK8 pa;
                #pragma unroll
                for (int j = 0; j < 4; ++j)
                    pa.p[j] = __builtin_amdgcn_cvt_pkrtz(w[8 * c + 2 * j], w[8 * c + 2 * j + 1]);
                U4H8 b0, b1; b0.u = vA[c * 2]; b1.u = vA[c * 2 + 1];
                acc0 = __builtin_amdgcn_mfma_f32_32x32x16_f16(pa.h, b0.h, acc0, 0, 0, 0);
                acc1 = __builtin_amdgcn_mfma_f32_32x32x16_f16(pa.h, b1.h, acc1, 0, 0, 0);
            }
            __builtin_amdgcn_s_setprio(0);
        }
        // ---- s = 1 (uses kc1, vB) ----
        if (t < 15) vld(t + 1, 0, vA);
        {
            f32x16 sim = (f32x16)(0.f);
            sim = __builtin_amdgcn_mfma_f32_32x32x16_f16(kc1.h, QB, sim, 0, 0, 0);
            float w[16];
            #pragma unroll
            for (int r = 0; r < 16; ++r) w[r] = __builtin_amdgcn_exp2f(sim[r]);
            float zp = 0.f;
            #pragma unroll
            for (int r = 0; r < 8; ++r) zp += (w[2 * r] + w[2 * r + 1]);
            z += zp;
            __builtin_amdgcn_s_setprio(1);
            #pragma unroll
            for (int c = 0; c < 2; ++c) {
                PK8 pa;
                #pragma unroll
                for (int j = 0; j < 4; ++j)
                    pa.p[j] = __builtin_amdgcn_cvt_pkrtz(w[8 * c + 2 * j], w[8 * c + 2 * j + 1]);
                U4H8 b0, b1; b0.u = vB[c * 2]; b1.u = vB[c * 2 + 1];
                acc0 = __builtin_amdgcn_mfma_f32_32x32x16_f16(pa.h, b0.h, acc0, 0, 0, 0);
                acc1 = __builtin_amdgcn_mfma_f32_32x32x16_f16(pa.h, b1.h, acc1, 0, 0, 0);
            }
            __builtin_amdgcn_s_setprio(0);
        }
        kc0 = kn0; kc1 = kn1;
    }

    // combine k-slices via LDS (stride 33 = conflict-free)
    const int cbase = (qw * 64 + lane) * 33;
    if (kslice == 1) {
        #pragma unroll
        for (int r = 0; r < 16; ++r) {
            fsh[cbase + r] = acc0[r];
            fsh[cbase + 16 + r] = acc1[r];
        }
        fsh[cbase + 32] = z;
    }
    __syncthreads();
    if (kslice == 0) {
        #pragma unroll
        for (int r = 0; r < 16; ++r) {
            acc0[r] += fsh[cbase + r];
            acc1[r] += fsh[cbase + 16 + r];
        }
        z += fsh[cbase + 32];
        z += __shfl_xor(z, 32, 64);     // combine hi halves
        float zinv = 1.0f / z;

        const int b = bh >> 3, h = bh & 7;
        #pragma unroll
        for (int r = 0; r < 16; ++r) {
            int qrow = (r & 3) + 8 * (r >> 2) + 4 * hi;
            float zi = __shfl(zinv, qrow, 32);
            size_t base = ((size_t)b * SS + q0 + qw * 32 + qrow) * EE + h * DKK + l31;
            attb[base]      = f2h(acc0[r] * zi);
            attb[base + 32] = f2h(acc1[r] * zi);
        }
    }
}

// ---------------------------------------------------------------------------
extern "C" void kernel_launch(void* const* d_in, const int* in_sizes, int n_in,
                              void* d_out, int out_size, void* d_ws, size_t ws_size,
                              hipStream_t stream)
{
    const float* x  = (const float*)d_in[0];
    const float* Wq = (const float*)d_in[1];
    const float* bq = (const float*)d_in[2];
    const float* Wk = (const float*)d_in[3];
    const float* bk = (const float*)d_in[4];
    const float* Wv = (const float*)d_in[5];
    const float* bv = (const float*)d_in[6];
    const float* Wo = (const float*)d_in[7];
    const float* bo = (const float*)d_in[8];
    // d_in[9] = kernel_params: unused (quantum circuit collapses to cos())

    char* w = (char*)d_ws;
    u16* xh    = (u16*)w;  w += (size_t)BS * EE * 2;               // 8 MB
    u16* xl    = (u16*)w;  w += (size_t)BS * EE * 2;               // 8 MB (aliases attb)
    u16* Wqk   = (u16*)w;  w += (size_t)128 * EE * 2;              // 128 KB
    u16* WvT   = (u16*)w;  w += (size_t)EE * EE * 2;               // 512 KB
    u16* WoT   = (u16*)w;  w += (size_t)EE * EE * 2;               // 512 KB
    u16* qf    = (u16*)w;  w += (size_t)BB * HH * SS * 8 * 2;      // 1 MB
    u16* kf    = (u16*)w;  w += (size_t)BB * HH * SS * 8 * 2;      // 1 MB
    u16* VT2   = (u16*)w;  w += (size_t)BB * HH * DKK * SS * 2;    // 8 MB
    u16* attb  = xl;   // alias: xl consumed by qk_mfma before attn writes attb
    float* out = (float*)d_out;

    // P1: x -> f16 hi/lo
    cvt2_kernel<<<dim3(BS * EE / 4 / 256), 256, 0, stream>>>(
        (const float4*)x, (uint2*)xh, (uint2*)xl, BS * EE / 4);
    // P2: Wq/Wk live cols -> packed transposed f16
    wqk_pack_kernel<<<dim3(128), 256, 0, stream>>>(Wq, Wk, Wqk);
    // P3: Wv, Wo -> transposed f16
    wtrans_kernel<<<dim3(8, 8), 256, 0, stream>>>(Wv, WvT);
    wtrans_kernel<<<dim3(8, 8), 256, 0, stream>>>(Wo, WoT);
    // A: Q/K projection (MFMA, 2-pass double-f16) + cos -> qf/kf f16
    qk_mfma_kernel<<<dim3(BS / 64, 2), 256, 0, stream>>>(
        xh, xl, Wqk, bq, bk, qf, kf);
    // B: V projection -> VT2 tau-baked cell layout (128x64-tile f16 MFMA)
    mfma_gemm_kernel<1><<<dim3(EE / 128, BS / 64), 256, 0, stream>>>(
        WvT, xh, bv, nullptr, VT2);
    // C: attention v10 -> attb f16
    attn_v10_kernel<<<dim3(1024), 256, 0, stream>>>(qf, kf, VT2, attb);
    // D: output projection + bias (128x64-tile f16 MFMA, fp32 out)
    mfma_gemm_kernel<0><<<dim3(BS / 128, EE / 64), 256, 0, stream>>>(
        attb, WoT, bo, out, nullptr);
}

// Round 15
// 80.753 us; speedup vs baseline: 1.5680x; 1.5680x over previous
//
#include <hip/hip_runtime.h>
#include <hip/hip_bf16.h>

// Problem constants
#define BB 4
#define SS 2048
#define EE 512
#define HH 8
#define DKK 64
#define NQQ 8
#define BS (BB * SS)   // 8192 rows

typedef __attribute__((ext_vector_type(4))) float f32x4;
typedef __attribute__((ext_vector_type(16))) float f32x16;
typedef __fp16 fp16x2 __attribute__((ext_vector_type(2)));   // cvt_pkrtz return type
typedef _Float16 f16x8 __attribute__((ext_vector_type(8)));
typedef unsigned short u16;
typedef unsigned int u32;

union U4H8 { uint4 u; f16x8 h; };
union PK8 { fp16x2 p[4]; f16x8 h; };

__device__ __forceinline__ u16 f2h(float f) {
    _Float16 hv = (_Float16)f;
    return *reinterpret_cast<u16*>(&hv);
}
__device__ __forceinline__ float h2f(u16 u) {
    _Float16 h = *reinterpret_cast<_Float16*>(&u);
    return (float)h;
}

// ---------------------------------------------------------------------------
// P1: x fp32 -> xh (f16) + xl (f16 residual).
// ---------------------------------------------------------------------------
__global__ __launch_bounds__(256) void cvt2_kernel(
    const float4* __restrict__ in, uint2* __restrict__ xh, uint2* __restrict__ xl, int n4)
{
    int i = blockIdx.x * 256 + threadIdx.x;
    if (i >= n4) return;
    float4 a = in[i];
    u16 h0 = f2h(a.x), h1 = f2h(a.y), h2 = f2h(a.z), h3 = f2h(a.w);
    u16 l0 = f2h(a.x - h2f(h0)), l1 = f2h(a.y - h2f(h1));
    u16 l2 = f2h(a.z - h2f(h2)), l3 = f2h(a.w - h2f(h3));
    xh[i] = make_uint2((u32)h0 | ((u32)h1 << 16), (u32)h2 | ((u32)h3 << 16));
    xl[i] = make_uint2((u32)l0 | ((u32)l1 << 16), (u32)l2 | ((u32)l3 << 16));
}

// ---------------------------------------------------------------------------
// P2: pack+transpose the 64 live Q/K weight cols each into Wqk[128][512] f16.
// ---------------------------------------------------------------------------
__global__ __launch_bounds__(256) void wqk_pack_kernel(
    const float* __restrict__ Wq, const float* __restrict__ Wk,
    u16* __restrict__ Wh)
{
    const int n = blockIdx.x;                  // 0..127
    const int col = (((n & 63) >> 3) << 6) | (n & 7);
    const float* src = (n < 64) ? Wq : Wk;
    for (int k = threadIdx.x; k < EE; k += 256) {
        Wh[(size_t)n * EE + k] = f2h(src[(size_t)k * EE + col]);
    }
}

// ---------------------------------------------------------------------------
// P3: W [512][512] f32 -> WT [512][512] f16 transposed. z=0: Wv, z=1: Wo
// (merged into one launch, grid (8,8,2)).
// ---------------------------------------------------------------------------
__global__ __launch_bounds__(256) void wtrans_kernel(
    const float* __restrict__ Wv, const float* __restrict__ Wo,
    u16* __restrict__ WvT, u16* __restrict__ WoT)
{
    __shared__ float ts[64][65];
    const float* W = blockIdx.z ? Wo : Wv;
    u16* WT = blockIdx.z ? WoT : WvT;
    const int kt0 = blockIdx.x * 64, nt0 = blockIdx.y * 64;
    const int tid = threadIdx.x;
    #pragma unroll
    for (int i = 0; i < 4; ++i) {
        int c = tid + i * 256;
        int kr = c >> 4, nc = (c & 15) * 4;
        float4 t = *reinterpret_cast<const float4*>(&W[(size_t)(kt0 + kr) * EE + nt0 + nc]);
        ts[kr][nc] = t.x; ts[kr][nc + 1] = t.y; ts[kr][nc + 2] = t.z; ts[kr][nc + 3] = t.w;
    }
    __syncthreads();
    const int n = tid >> 2, k0 = (tid & 3) * 16;
    u32 o[8];
    #pragma unroll
    for (int j = 0; j < 8; ++j) {
        o[j] = (u32)f2h(ts[k0 + 2 * j][n]) | ((u32)f2h(ts[k0 + 2 * j + 1][n]) << 16);
    }
    uint4* dst = reinterpret_cast<uint4*>(&WT[(size_t)(nt0 + n) * EE + kt0 + k0]);
    dst[0] = make_uint4(o[0], o[1], o[2], o[3]);
    dst[1] = make_uint4(o[4], o[5], o[6], o[7]);
}

// ---------------------------------------------------------------------------
// QK projection via MFMA, double-f16 (2 passes: xh*W + xl*W). Reg-staged
// prefetch (round-12 verified). Epilogue: cos(proj + bias); K pre-scaled
// by log2(e) so attention uses exp2. Store f16 qf/kf.
// ---------------------------------------------------------------------------
__global__ __launch_bounds__(256) void qk_mfma_kernel(
    const u16* __restrict__ xh, const u16* __restrict__ xl,
    const u16* __restrict__ Wh,
    const float* __restrict__ bq, const float* __restrict__ bk,
    u16* __restrict__ qf, u16* __restrict__ kf)
{
    __shared__ u16 Asl[64 * 64];
    __shared__ u16 Bsl[64 * 64];

    const int tid = threadIdx.x;
    const int lane = tid & 63;
    const int ww = tid >> 6;
    const int wr = ww >> 1, wc = ww & 1;
    const int tx = lane & 15, tyq = lane >> 4;
    const int m0 = blockIdx.x * 64;
    const int isK = blockIdx.y;
    const int nbase = isK * 64;

    const int c0 = tid, c1 = tid + 256;
    const int r0 = c0 >> 3, o0 = (c0 & 7) * 8, d0 = r0 * 64 + (((c0 & 7) ^ (r0 & 7)) * 8);
    const int r1 = c1 >> 3, o1 = (c1 & 7) * 8, d1 = r1 * 64 + (((c1 & 7) ^ (r1 & 7)) * 8);

    uint4 pa0, pa1, pb0, pb1;
    auto ldi = [&](int it) {
        int pass = it >> 3, k0 = (it & 7) * 64;
        const u16* Ab = pass ? xl : xh;
        pa0 = *reinterpret_cast<const uint4*>(&Ab[(size_t)(m0 + r0) * EE + k0 + o0]);
        pb0 = *reinterpret_cast<const uint4*>(&Wh[(size_t)(nbase + r0) * EE + k0 + o0]);
        pa1 = *reinterpret_cast<const uint4*>(&Ab[(size_t)(m0 + r1) * EE + k0 + o1]);
        pb1 = *reinterpret_cast<const uint4*>(&Wh[(size_t)(nbase + r1) * EE + k0 + o1]);
    };
    auto st = [&]() {
        *reinterpret_cast<uint4*>(&Asl[d0]) = pa0;
        *reinterpret_cast<uint4*>(&Bsl[d0]) = pb0;
        *reinterpret_cast<uint4*>(&Asl[d1]) = pa1;
        *reinterpret_cast<uint4*>(&Bsl[d1]) = pb1;
    };

    f32x4 acc[2][2];
    #pragma unroll
    for (int mt = 0; mt < 2; ++mt)
        #pragma unroll
        for (int nt = 0; nt < 2; ++nt) acc[mt][nt] = (f32x4)(0.f);

    const int bkx = tx & 7;
    ldi(0);
    for (int it = 0; it < 16; ++it) {
        __syncthreads();
        st();
        if (it < 15) ldi(it + 1);
        __syncthreads();
        #pragma unroll
        for (int kb = 0; kb < 2; ++kb) {
            f16x8 af[2], bfg[2];
            const int kblk = ((kb * 4 + tyq) ^ bkx) * 8;
            #pragma unroll
            for (int mt = 0; mt < 2; ++mt)
                af[mt] = *reinterpret_cast<const f16x8*>(&Asl[(wr * 32 + mt * 16 + tx) * 64 + kblk]);
            #pragma unroll
            for (int nt = 0; nt < 2; ++nt)
                bfg[nt] = *reinterpret_cast<const f16x8*>(&Bsl[(wc * 32 + nt * 16 + tx) * 64 + kblk]);
            #pragma unroll
            for (int mt = 0; mt < 2; ++mt)
                #pragma unroll
                for (int nt = 0; nt < 2; ++nt)
                    acc[mt][nt] = __builtin_amdgcn_mfma_f32_16x16x32_f16(
                        af[mt], bfg[nt], acc[mt][nt], 0, 0, 0);
        }
    }

    const float* bias = isK ? bk : bq;
    const float scale = isK ? 1.44269504f : 1.0f;   // log2(e) prescale on K
    u16* dst = isK ? kf : qf;
    #pragma unroll
    for (int mt = 0; mt < 2; ++mt) {
        #pragma unroll
        for (int nt = 0; nt < 2; ++nt) {
            int nl = wc * 32 + nt * 16 + tx;
            int h = nl >> 3, f = nl & 7;
            float bcol = bias[h * 64 + f];
            #pragma unroll
            for (int r = 0; r < 4; ++r) {
                int s = m0 + wr * 32 + mt * 16 + tyq * 4 + r;
                float c = __cosf(acc[mt][nt][r] + bcol) * scale;
                size_t bh = (size_t)((s >> 11) * HH + h);
                dst[(bh * SS + (s & 2047)) * 8 + f] = f2h(c);
            }
        }
    }
}

// ---------------------------------------------------------------------------
// f16 MFMA GEMM, 64x64 tile (round-12 verified): out[m][n] = A.Bm^T + bias.
// MODE 0: out fp32 [8192][512], bias[n] (out-proj).
// MODE 1: out f16 VT2 cells (tau-baked): addr(u16) = cell*512 + d*8 + slot,
//   cell = (k>>4)*2 + ((k>>2)&1), slot = (k&3) + 4*((k>>3)&1).
// ---------------------------------------------------------------------------
template<int MODE>
__global__ __launch_bounds__(256) void mfma_gemm_kernel(
    const u16* __restrict__ A, const u16* __restrict__ Bm,
    const float* __restrict__ bias, float* __restrict__ outf, u16* __restrict__ outb)
{
    __shared__ u16 smem[8448];   // Asl = smem[0..4095], Bsl = smem[4096..8191]
    u16* Asl = smem;
    u16* Bsl = smem + 4096;

    const int tid = threadIdx.x;
    const int lane = tid & 63;
    const int ww = tid >> 6;
    const int wr = ww >> 1, wc = ww & 1;
    const int tx = lane & 15, tyq = lane >> 4;
    const int m0 = blockIdx.x * 64, n0 = blockIdx.y * 64;

    const int c0 = tid, c1 = tid + 256;
    const int r0 = c0 >> 3, o0 = (c0 & 7) * 8, d0 = r0 * 64 + (((c0 & 7) ^ (r0 & 7)) * 8);
    const int r1 = c1 >> 3, o1 = (c1 & 7) * 8, d1 = r1 * 64 + (((c1 & 7) ^ (r1 & 7)) * 8);

    uint4 pa0, pa1, pb0, pb1;
    auto ld = [&](int ks) {
        int k0 = ks * 64;
        pa0 = *reinterpret_cast<const uint4*>(&A [(size_t)(m0 + r0) * EE + k0 + o0]);
        pb0 = *reinterpret_cast<const uint4*>(&Bm[(size_t)(n0 + r0) * EE + k0 + o0]);
        pa1 = *reinterpret_cast<const uint4*>(&A [(size_t)(m0 + r1) * EE + k0 + o1]);
        pb1 = *reinterpret_cast<const uint4*>(&Bm[(size_t)(n0 + r1) * EE + k0 + o1]);
    };
    auto st = [&]() {
        *reinterpret_cast<uint4*>(&Asl[d0]) = pa0;
        *reinterpret_cast<uint4*>(&Bsl[d0]) = pb0;
        *reinterpret_cast<uint4*>(&Asl[d1]) = pa1;
        *reinterpret_cast<uint4*>(&Bsl[d1]) = pb1;
    };

    f32x4 acc[2][2];
    #pragma unroll
    for (int mt = 0; mt < 2; ++mt)
        #pragma unroll
        for (int nt = 0; nt < 2; ++nt) acc[mt][nt] = (f32x4)(0.f);

    const int bkx = tx & 7;
    ld(0);
    for (int ks = 0; ks < 8; ++ks) {
        __syncthreads();
        st();
        if (ks < 7) ld(ks + 1);
        __syncthreads();
        #pragma unroll
        for (int kb = 0; kb < 2; ++kb) {
            f16x8 af[2], bfg[2];
            const int kblk = ((kb * 4 + tyq) ^ bkx) * 8;
            #pragma unroll
            for (int mt = 0; mt < 2; ++mt)
                af[mt] = *reinterpret_cast<const f16x8*>(&Asl[(wr * 32 + mt * 16 + tx) * 64 + kblk]);
            #pragma unroll
            for (int nt = 0; nt < 2; ++nt)
                bfg[nt] = *reinterpret_cast<const f16x8*>(&Bsl[(wc * 32 + nt * 16 + tx) * 64 + kblk]);
            #pragma unroll
            for (int mt = 0; mt < 2; ++mt)
                #pragma unroll
                for (int nt = 0; nt < 2; ++nt)
                    acc[mt][nt] = __builtin_amdgcn_mfma_f32_16x16x32_f16(
                        af[mt], bfg[nt], acc[mt][nt], 0, 0, 0);
        }
    }

    if (MODE == 0) {
        #pragma unroll
        for (int mt = 0; mt < 2; ++mt) {
            #pragma unroll
            for (int nt = 0; nt < 2; ++nt) {
                int gcol = n0 + wc * 32 + nt * 16 + tx;
                float bcol = bias[gcol];
                #pragma unroll
                for (int r = 0; r < 4; ++r) {
                    int grow = m0 + wr * 32 + mt * 16 + tyq * 4 + r;
                    outf[(size_t)grow * EE + gcol] = acc[mt][nt][r] + bcol;
                }
            }
        }
    } else {
        // retile: stage C as L[d_local][k_local] f16 in LDS (stride 66 u16)
        __syncthreads();   // main-loop LDS reads complete before reuse
        #pragma unroll
        for (int mt = 0; mt < 2; ++mt) {
            #pragma unroll
            for (int nt = 0; nt < 2; ++nt) {
                int kl = wc * 32 + nt * 16 + tx;
                #pragma unroll
                for (int r = 0; r < 4; ++r) {
                    int dl = wr * 32 + mt * 16 + tyq * 4 + r;
                    float vb = acc[mt][nt][r] + bias[m0 + dl];
                    smem[dl * 66 + kl] = f2h(vb);
                }
            }
        }
        __syncthreads();
        const size_t slab = (size_t)((n0 >> 11) * HH + (m0 >> 6)) * (SS * DKK);
        const int cell0 = (n0 & 2047) >> 3;
        #pragma unroll
        for (int i = 0; i < 2; ++i) {
            int item = tid + i * 256;
            int d = item & 63, ci = item >> 6;
            int kb = 16 * (ci >> 1) + 4 * (ci & 1);
            u16 g[8];
            #pragma unroll
            for (int j = 0; j < 8; ++j) {
                int klocal = kb + (j & 3) + 8 * (j >> 2);
                g[j] = smem[d * 66 + klocal];
            }
            uint4 p;
            p.x = (u32)g[0] | ((u32)g[1] << 16);
            p.y = (u32)g[2] | ((u32)g[3] << 16);
            p.z = (u32)g[4] | ((u32)g[5] << 16);
            p.w = (u32)g[6] | ((u32)g[7] << 16);
            *reinterpret_cast<uint4*>(&outb[slab + (size_t)(cell0 + ci) * 512 + d * 8]) = p;
        }
    }
}

// ---------------------------------------------------------------------------
// Attention v10 (round-12/13 verified): barrier-free LDS-free main loop,
// direct-L2 VT2 cell reads, exp2 on pre-scaled K, setprio around PV,
// pairwise cvt_pkrtz PA packing. 4 waves = 2 q-sub x 2 k-slices. Grid 1024.
// ---------------------------------------------------------------------------
__global__ __launch_bounds__(256, 4) void attn_v10_kernel(
    const u16* __restrict__ qf, const u16* __restrict__ kf,
    const u16* __restrict__ VT2, u16* __restrict__ attb)
{
    __shared__ float fsh[128 * 33];   // 16.9 KB combine scratch

    const int tid = threadIdx.x;
    const int lane = tid & 63;
    const int wv = tid >> 6;
    const int kslice = wv >> 1;
    const int qw = wv & 1;
    const int l31 = lane & 31;
    const int hi = lane >> 5;

    // XCD-aware swizzle: all 32 q-blocks of a (b,h) on one XCD
    const int bid = blockIdx.x;
    const int xcd = bid & 7, sub = bid >> 3;
    const int bh = (xcd << 2) | (sub >> 5);
    const int q0 = (sub & 31) * 64;

    const u16* __restrict__ qfb = qf + (size_t)bh * SS * 8;
    const u16* __restrict__ kfb = kf + (size_t)bh * SS * 8;
    const u16* __restrict__ V2b = VT2 + (size_t)bh * SS * DKK;

    const uint4 z4 = make_uint4(0u, 0u, 0u, 0u);

    // Q B-frag (loop-invariant): B[k=8hi+j][n=q=l31]; feats 8..15 pad=0
    U4H8 qb;
    qb.u = hi ? z4 : *reinterpret_cast<const uint4*>(&qfb[(size_t)(q0 + qw * 32 + l31) * 8]);
    const f16x8 QB = qb.h;

    f32x16 acc0 = (f32x16)(0.f), acc1 = (f32x16)(0.f);
    float z = 0.f;

    const int ks_off = kslice * 1024;

    // V frag loader: (t, s) -> 4 uint4 [c*2 + dblk]
    auto vld = [&](int t, int s, uint4* dst) {
        const int K0 = ks_off + t * 64 + s * 32;
        #pragma unroll
        for (int c = 0; c < 2; ++c) {
            const size_t cb = (size_t)((((K0 >> 4) + c) << 1) + hi) * 512;
            dst[c * 2]     = *reinterpret_cast<const uint4*>(&V2b[cb + l31 * 8]);
            dst[c * 2 + 1] = *reinterpret_cast<const uint4*>(&V2b[cb + (32 + l31) * 8]);
        }
    };

    U4H8 kc0, kc1, kn0, kn1;
    auto ldk = [&](int t, U4H8& a, U4H8& b) {
        int kt = ks_off + t * 64;
        a.u = hi ? z4 : *reinterpret_cast<const uint4*>(&kfb[(size_t)(kt + l31) * 8]);
        b.u = hi ? z4 : *reinterpret_cast<const uint4*>(&kfb[(size_t)(kt + 32 + l31) * 8]);
    };

    uint4 vA[4], vB[4];
    ldk(0, kc0, kc1);
    vld(0, 0, vA);

    for (int t = 0; t < 16; ++t) {
        // ---- s = 0 (uses kc0, vA) ----
        vld(t, 1, vB);
        if (t < 15) ldk(t + 1, kn0, kn1);
        {
            f32x16 sim = (f32x16)(0.f);
            sim = __builtin_amdgcn_mfma_f32_32x32x16_f16(kc0.h, QB, sim, 0, 0, 0);
            float w[16];
            #pragma unroll
            for (int r = 0; r < 16; ++r) w[r] = __builtin_amdgcn_exp2f(sim[r]);  // K pre-scaled
            float zp = 0.f;
            #pragma unroll
            for (int r = 0; r < 8; ++r) zp += (w[2 * r] + w[2 * r + 1]);
            z += zp;
            __builtin_amdgcn_s_setprio(1);
            #pragma unroll
            for (int c = 0; c < 2; ++c) {
                PK8 pa;
                #pragma unroll
                for (int j = 0; j < 4; ++j)
                    pa.p[j] = __builtin_amdgcn_cvt_pkrtz(w[8 * c + 2 * j], w[8 * c + 2 * j + 1]);
                U4H8 b0, b1; b0.u = vA[c * 2]; b1.u = vA[c * 2 + 1];
                acc0 = __builtin_amdgcn_mfma_f32_32x32x16_f16(pa.h, b0.h, acc0, 0, 0, 0);
                acc1 = __builtin_amdgcn_mfma_f32_32x32x16_f16(pa.h, b1.h, acc1, 0, 0, 0);
            }
            __builtin_amdgcn_s_setprio(0);
        }
        // ---- s = 1 (uses kc1, vB) ----
        if (t < 15) vld(t + 1, 0, vA);
        {
            f32x16 sim = (f32x16)(0.f);
            sim = __builtin_amdgcn_mfma_f32_32x32x16_f16(kc1.h, QB, sim, 0, 0, 0);
            float w[16];
            #pragma unroll
            for (int r = 0; r < 16; ++r) w[r] = __builtin_amdgcn_exp2f(sim[r]);
            float zp = 0.f;
            #pragma unroll
            for (int r = 0; r < 8; ++r) zp += (w[2 * r] + w[2 * r + 1]);
            z += zp;
            __builtin_amdgcn_s_setprio(1);
            #pragma unroll
            for (int c = 0; c < 2; ++c) {
                PK8 pa;
                #pragma unroll
                for (int j = 0; j < 4; ++j)
                    pa.p[j] = __builtin_amdgcn_cvt_pkrtz(w[8 * c + 2 * j], w[8 * c + 2 * j + 1]);
                U4H8 b0, b1; b0.u = vB[c * 2]; b1.u = vB[c * 2 + 1];
                acc0 = __builtin_amdgcn_mfma_f32_32x32x16_f16(pa.h, b0.h, acc0, 0, 0, 0);
                acc1 = __builtin_amdgcn_mfma_f32_32x32x16_f16(pa.h, b1.h, acc1, 0, 0, 0);
            }
            __builtin_amdgcn_s_setprio(0);
        }
        kc0 = kn0; kc1 = kn1;
    }

    // combine k-slices via LDS (stride 33 = conflict-free)
    const int cbase = (qw * 64 + lane) * 33;
    if (kslice == 1) {
        #pragma unroll
        for (int r = 0; r < 16; ++r) {
            fsh[cbase + r] = acc0[r];
            fsh[cbase + 16 + r] = acc1[r];
        }
        fsh[cbase + 32] = z;
    }
    __syncthreads();
    if (kslice == 0) {
        #pragma unroll
        for (int r = 0; r < 16; ++r) {
            acc0[r] += fsh[cbase + r];
            acc1[r] += fsh[cbase + 16 + r];
        }
        z += fsh[cbase + 32];
        z += __shfl_xor(z, 32, 64);     // combine hi halves
        float zinv = 1.0f / z;

        const int b = bh >> 3, h = bh & 7;
        #pragma unroll
        for (int r = 0; r < 16; ++r) {
            int qrow = (r & 3) + 8 * (r >> 2) + 4 * hi;
            float zi = __shfl(zinv, qrow, 32);
            size_t base = ((size_t)b * SS + q0 + qw * 32 + qrow) * EE + h * DKK + l31;
            attb[base]      = f2h(acc0[r] * zi);
            attb[base + 32] = f2h(acc1[r] * zi);
        }
    }
}

// ---------------------------------------------------------------------------
extern "C" void kernel_launch(void* const* d_in, const int* in_sizes, int n_in,
                              void* d_out, int out_size, void* d_ws, size_t ws_size,
                              hipStream_t stream)
{
    const float* x  = (const float*)d_in[0];
    const float* Wq = (const float*)d_in[1];
    const float* bq = (const float*)d_in[2];
    const float* Wk = (const float*)d_in[3];
    const float* bk = (const float*)d_in[4];
    const float* Wv = (const float*)d_in[5];
    const float* bv = (const float*)d_in[6];
    const float* Wo = (const float*)d_in[7];
    const float* bo = (const float*)d_in[8];
    // d_in[9] = kernel_params: unused (quantum circuit collapses to cos())

    char* w = (char*)d_ws;
    u16* xh    = (u16*)w;  w += (size_t)BS * EE * 2;               // 8 MB
    u16* xl    = (u16*)w;  w += (size_t)BS * EE * 2;               // 8 MB (aliases attb)
    u16* Wqk   = (u16*)w;  w += (size_t)128 * EE * 2;              // 128 KB
    u16* WvT   = (u16*)w;  w += (size_t)EE * EE * 2;               // 512 KB
    u16* WoT   = (u16*)w;  w += (size_t)EE * EE * 2;               // 512 KB
    u16* qf    = (u16*)w;  w += (size_t)BB * HH * SS * 8 * 2;      // 1 MB
    u16* kf    = (u16*)w;  w += (size_t)BB * HH * SS * 8 * 2;      // 1 MB
    u16* VT2   = (u16*)w;  w += (size_t)BB * HH * DKK * SS * 2;    // 8 MB
    u16* attb  = xl;   // alias: xl consumed by qk_mfma before attn writes attb
    float* out = (float*)d_out;

    // P1: x -> f16 hi/lo
    cvt2_kernel<<<dim3(BS * EE / 4 / 256), 256, 0, stream>>>(
        (const float4*)x, (uint2*)xh, (uint2*)xl, BS * EE / 4);
    // P2: Wq/Wk live cols -> packed transposed f16
    wqk_pack_kernel<<<dim3(128), 256, 0, stream>>>(Wq, Wk, Wqk);
    // P3: Wv + Wo -> transposed f16 (merged, one launch)
    wtrans_kernel<<<dim3(8, 8, 2), 256, 0, stream>>>(Wv, Wo, WvT, WoT);
    // A: Q/K projection (MFMA, 2-pass double-f16) + cos -> qf/kf f16
    qk_mfma_kernel<<<dim3(BS / 64, 2), 256, 0, stream>>>(
        xh, xl, Wqk, bq, bk, qf, kf);
    // B: V projection -> VT2 tau-baked cell layout (64x64 f16 MFMA)
    mfma_gemm_kernel<1><<<dim3(EE / 64, BS / 64), 256, 0, stream>>>(
        WvT, xh, bv, nullptr, VT2);
    // C: attention v10 -> attb f16
    attn_v10_kernel<<<dim3(1024), 256, 0, stream>>>(qf, kf, VT2, attb);
    // D: output projection + bias (64x64 f16 MFMA, fp32 out)
    mfma_gemm_kernel<0><<<dim3(BS / 64, EE / 64), 256, 0, stream>>>(
        attb, WoT, bo, out, nullptr);
}